// Round 1
// baseline (128.057 us; speedup 1.0000x reference)
//
#include <hip/hip_runtime.h>
#include <math.h>

// CapsuleLinear routing, fp32.
// B=64, N(in_caps)=1152, I(in_len)=8, O(out_caps)=64, L(out_len)=16, 3 iters.
// One block per (b,o): 384 threads x 3 rows/thread; priors kept in VGPRs.

#define NCAPS 1152
#define ILEN  8
#define OCAPS 64
#define OLEN  16
#define T     384      // 6 waves; 1152 / 384 = 3 rows per thread
#define RPT   3
#define NWAVES 6
#define NITER 3

__device__ __forceinline__ float block_reduce_max(float v, float* redsc, int lane, int wid) {
    #pragma unroll
    for (int off = 1; off < 64; off <<= 1) v = fmaxf(v, __shfl_xor(v, off, 64));
    if (lane == 0) redsc[wid] = v;
    __syncthreads();
    float r = redsc[0];
    #pragma unroll
    for (int ww = 1; ww < NWAVES; ++ww) r = fmaxf(r, redsc[ww]);
    __syncthreads();
    return r;
}

__device__ __forceinline__ float block_reduce_sum(float v, float* redsc, int lane, int wid) {
    #pragma unroll
    for (int off = 1; off < 64; off <<= 1) v += __shfl_xor(v, off, 64);
    if (lane == 0) redsc[wid] = v;
    __syncthreads();
    float r = redsc[0];
    #pragma unroll
    for (int ww = 1; ww < NWAVES; ++ww) r += redsc[ww];
    __syncthreads();
    return r;
}

// 16-component block-wide sum of v[16]; result*scale written to outv[0..15].
// Halving butterfly: comps halve each step; lane bit pattern -> component
// c = b0*8 + b1*4 + b2*2 + b3 (bit-reversed low nibble).
#define BSTAGE(OFF, H)                                              \
    {                                                               \
        const bool up = (lane & (OFF)) != 0;                        \
        _Pragma("unroll")                                           \
        for (int j = 0; j < (H); ++j) {                             \
            float keep = up ? v[(H) + j] : v[j];                    \
            float send = up ? v[j] : v[(H) + j];                    \
            v[j] = keep + __shfl_xor(send, (OFF), 64);              \
        }                                                           \
    }

__device__ __forceinline__ void vec16_block_reduce(float* v, float scale,
                                                   float (*red16)[16], float* outv,
                                                   int tid, int lane, int wid) {
    BSTAGE(1, 8)
    BSTAGE(2, 4)
    BSTAGE(4, 2)
    BSTAGE(8, 1)
    float v0 = v[0];
    v0 += __shfl_xor(v0, 16, 64);
    v0 += __shfl_xor(v0, 32, 64);
    if (lane < 16) {
        const int c = ((lane & 1) << 3) | ((lane & 2) << 1) | ((lane & 4) >> 1) | ((lane & 8) >> 3);
        red16[wid][c] = v0;
    }
    __syncthreads();
    if (tid < 16) {
        float t = red16[0][tid];
        #pragma unroll
        for (int ww = 1; ww < NWAVES; ++ww) t += red16[ww][tid];
        outv[tid] = t * scale;
    }
    __syncthreads();
}

__global__ __launch_bounds__(T) void caps_kernel(const float* __restrict__ x,
                                                 const float* __restrict__ w,
                                                 float* __restrict__ dout,
                                                 int nblocks_out_base) {
    const int tid  = threadIdx.x;
    const int lane = tid & 63;
    const int wid  = tid >> 6;
    const int o = blockIdx.x & (OCAPS - 1);
    const int b = blockIdx.x >> 6;

    __shared__ __align__(16) float ws[OLEN * ILEN];   // weight[o], 128 floats
    __shared__ float red16[NWAVES][16];
    __shared__ float redsc[NWAVES];
    __shared__ float outv[16];

    if (tid < OLEN * ILEN) ws[tid] = w[o * OLEN * ILEN + tid];

    // x rows for this thread -> registers (each row used only by its owner)
    const float* xb = x + (size_t)b * NCAPS * ILEN;
    float xr[RPT][ILEN];
    #pragma unroll
    for (int k = 0; k < RPT; ++k) {
        const float4* q = (const float4*)(xb + (size_t)(tid + k * T) * ILEN);
        float4 a = q[0], c = q[1];
        xr[k][0] = a.x; xr[k][1] = a.y; xr[k][2] = a.z; xr[k][3] = a.w;
        xr[k][4] = c.x; xr[k][5] = c.y; xr[k][6] = c.z; xr[k][7] = c.w;
    }
    __syncthreads();

    // priors p[k][l] = dot(w[l,:], x[n,:]) — kept in VGPRs for all iterations
    float p[RPT][OLEN];
    #pragma unroll
    for (int l = 0; l < OLEN; ++l) {
        const float4 w0 = *(const float4*)&ws[l * ILEN];
        const float4 w1 = *(const float4*)&ws[l * ILEN + 4];
        #pragma unroll
        for (int k = 0; k < RPT; ++k) {
            float s = xr[k][0] * w0.x;
            s = fmaf(xr[k][1], w0.y, s);
            s = fmaf(xr[k][2], w0.z, s);
            s = fmaf(xr[k][3], w0.w, s);
            s = fmaf(xr[k][4], w1.x, s);
            s = fmaf(xr[k][5], w1.y, s);
            s = fmaf(xr[k][6], w1.z, s);
            s = fmaf(xr[k][7], w1.w, s);
            p[k][l] = s;
        }
    }

    // initial centroid: mean over n
    {
        float v[OLEN];
        #pragma unroll
        for (int l = 0; l < OLEN; ++l) v[l] = p[0][l] + p[1][l] + p[2][l];
        vec16_block_reduce(v, 1.0f / (float)NCAPS, red16, outv, tid, lane, wid);
    }

    float e[RPT] = {0.f, 0.f, 0.f};
    float invZ = 0.f;

    #pragma unroll 1
    for (int it = 0; it < NITER; ++it) {
        // read centroid, normalize locally (identical on every thread)
        float on[OLEN];
        #pragma unroll
        for (int l = 0; l < OLEN; ++l) on[l] = outv[l];
        float n2 = 0.f;
        #pragma unroll
        for (int l = 0; l < OLEN; ++l) n2 = fmaf(on[l], on[l], n2);
        const float inv = 1.0f / fmaxf(sqrtf(n2), 1e-12f);

        // logits = priors . out_n
        float lg[RPT];
        #pragma unroll
        for (int k = 0; k < RPT; ++k) {
            float s = 0.f;
            #pragma unroll
            for (int l = 0; l < OLEN; ++l) s = fmaf(p[k][l], on[l], s);
            lg[k] = s * inv;
        }

        // softmax over n (stable)
        float mx = fmaxf(lg[0], fmaxf(lg[1], lg[2]));
        mx = block_reduce_max(mx, redsc, lane, wid);
        float se = 0.f;
        #pragma unroll
        for (int k = 0; k < RPT; ++k) { e[k] = __expf(lg[k] - mx); se += e[k]; }
        const float Z = block_reduce_sum(se, redsc, lane, wid);
        invZ = 1.0f / Z;

        // out = sum_n probs * priors  (fold invZ into the reduce scale)
        float v[OLEN];
        #pragma unroll
        for (int l = 0; l < OLEN; ++l) {
            float s = e[0] * p[0][l];
            s = fmaf(e[1], p[1][l], s);
            s = fmaf(e[2], p[2][l], s);
            v[l] = s;
        }
        vec16_block_reduce(v, invZ, red16, outv, tid, lane, wid);
    }

    // outputs: out [B*O*16] then probs [B*O*1152]
    float* outp  = dout + (size_t)blockIdx.x * OLEN;
    float* probp = dout + (size_t)nblocks_out_base + (size_t)blockIdx.x * NCAPS;
    #pragma unroll
    for (int k = 0; k < RPT; ++k) probp[tid + k * T] = e[k] * invZ;
    if (tid < OLEN) outp[tid] = outv[tid];
}

extern "C" void kernel_launch(void* const* d_in, const int* in_sizes, int n_in,
                              void* d_out, int out_size, void* d_ws, size_t ws_size,
                              hipStream_t stream) {
    const float* x = (const float*)d_in[0];
    const float* w = (const float*)d_in[1];
    float* out = (float*)d_out;
    const int Bv = in_sizes[0] / (NCAPS * ILEN);   // 64
    const int nblocks = Bv * OCAPS;                // 4096
    const int out_base = nblocks * OLEN;           // 65536: probs start here
    caps_kernel<<<dim3(nblocks), dim3(T), 0, stream>>>(x, w, out, out_base);
}

// Round 2
// 78.928 us; speedup vs baseline: 1.6224x; 1.6224x over previous
//
#include <hip/hip_runtime.h>
#include <math.h>

// CapsuleLinear routing, fp32 — priors eliminated algebraically.
// logits_n = x_n . (W^T out_hat);  out = W . (sum_n p_n x_n)
// B=64, N=1152, I=8, O=64, L=16, 3 iters. One block per (b,o).
// T=128 (2 waves), 9 rows/thread; x rows live in VGPRs.

#define NCAPS 1152
#define ILEN  8
#define OCAPS 64
#define OLEN  16
#define T     128
#define RPT   9        // 1152 / 128
#define NW    2
#define NITER 3

// In-wave halving butterfly stage for 8-component vector reduce.
#define BSTAGE(OFF, H)                                              \
    {                                                               \
        const bool up = (lane & (OFF)) != 0;                        \
        _Pragma("unroll")                                           \
        for (int j = 0; j < (H); ++j) {                             \
            float keep = up ? s[(H) + j] : s[j];                    \
            float send = up ? s[j] : s[(H) + j];                    \
            s[j] = keep + __shfl_xor(send, (OFF), 64);              \
        }                                                           \
    }

__global__ __launch_bounds__(T, 4) void caps_kernel(const float* __restrict__ x,
                                                    const float* __restrict__ w,
                                                    float* __restrict__ dout,
                                                    int probs_base) {
    const int tid  = threadIdx.x;
    const int lane = tid & 63;
    const int wid  = tid >> 6;
    const int o = blockIdx.x & (OCAPS - 1);
    const int b = blockIdx.x >> 6;

    __shared__ __align__(16) float ws[OLEN * ILEN];  // weight[o], row-major [l][i]
    __shared__ float red[NW][ILEN];
    __shared__ float redz[NW];
    __shared__ float ylds[ILEN];                     // y = W^T out_hat

    ws[tid] = w[o * OLEN * ILEN + tid];              // T==128 covers exactly

    // x rows -> registers (coalesced float4 pairs)
    const float* xb = x + (size_t)b * NCAPS * ILEN;
    float xr[RPT][ILEN];
    #pragma unroll
    for (int k = 0; k < RPT; ++k) {
        const float4* q = (const float4*)(xb + (size_t)(tid + k * T) * ILEN);
        float4 a = q[0], c = q[1];
        xr[k][0] = a.x; xr[k][1] = a.y; xr[k][2] = a.z; xr[k][3] = a.w;
        xr[k][4] = c.x; xr[k][5] = c.y; xr[k][6] = c.z; xr[k][7] = c.w;
    }

    float e[RPT];

    // it==0: initial centroid (e=1).  it=1..3: routing iterations.
    #pragma unroll
    for (int it = 0; it <= NITER; ++it) {
        if (it > 0) {
            float yv[ILEN];
            #pragma unroll
            for (int i = 0; i < ILEN; ++i) yv[i] = ylds[i];
            #pragma unroll
            for (int k = 0; k < RPT; ++k) {
                float lg = xr[k][0] * yv[0];
                #pragma unroll
                for (int i = 1; i < ILEN; ++i) lg = fmaf(xr[k][i], yv[i], lg);
                e[k] = __expf(lg);   // max-subtraction skipped: |lg| <~ 10
            }
        } else {
            #pragma unroll
            for (int k = 0; k < RPT; ++k) e[k] = 1.0f;
        }

        // partial weighted sum s[8] and partition z
        float s[ILEN];
        #pragma unroll
        for (int i = 0; i < ILEN; ++i) {
            float acc = e[0] * xr[0][i];
            #pragma unroll
            for (int k = 1; k < RPT; ++k) acc = fmaf(e[k], xr[k][i], acc);
            s[i] = acc;
        }
        float z = e[0];
        #pragma unroll
        for (int k = 1; k < RPT; ++k) z += e[k];

        // in-wave reduce: s (8 comps, halving butterfly) + z (scalar chain)
        BSTAGE(1, 4)
        BSTAGE(2, 2)
        BSTAGE(4, 1)
        float s0 = s[0];
        s0 += __shfl_xor(s0, 8, 64);
        s0 += __shfl_xor(s0, 16, 64);
        s0 += __shfl_xor(s0, 32, 64);
        #pragma unroll
        for (int off = 1; off < 64; off <<= 1) z += __shfl_xor(z, off, 64);

        if (lane < 8) {
            const int c = ((lane & 1) << 2) | (lane & 2) | ((lane & 4) >> 2); // bitrev3
            red[wid][c] = s0;
        }
        if (lane == 0) redz[wid] = z;
        __syncthreads();

        const float zt   = redz[0] + redz[1];
        const float zinv = 1.0f / zt;

        if (it < NITER) {
            // wave 0: out = zinv * W s;  y = W^T (out/||out||)  -> ylds
            if (wid == 0) {
                float sv = (lane < 8) ? (red[0][lane] + red[1][lane]) : 0.0f;
                float sb[ILEN];
                #pragma unroll
                for (int i = 0; i < ILEN; ++i) sb[i] = __shfl(sv, i, 64);
                const int l16 = lane & 15;
                const float4 w0 = *(const float4*)&ws[l16 * ILEN];
                const float4 w1 = *(const float4*)&ws[l16 * ILEN + 4];
                float outl = w0.x * sb[0];
                outl = fmaf(w0.y, sb[1], outl);
                outl = fmaf(w0.z, sb[2], outl);
                outl = fmaf(w0.w, sb[3], outl);
                outl = fmaf(w1.x, sb[4], outl);
                outl = fmaf(w1.y, sb[5], outl);
                outl = fmaf(w1.z, sb[6], outl);
                outl = fmaf(w1.w, sb[7], outl);
                outl *= zinv;                       // replicated: lane -> lane&15
                float n2 = outl * outl;
                n2 += __shfl_xor(n2, 1, 64);
                n2 += __shfl_xor(n2, 2, 64);
                n2 += __shfl_xor(n2, 4, 64);
                n2 += __shfl_xor(n2, 8, 64);
                const float inv = 1.0f / fmaxf(sqrtf(n2), 1e-12f);
                float ob[OLEN];
                #pragma unroll
                for (int l = 0; l < OLEN; ++l) ob[l] = __shfl(outl, l, 64);
                const int i8 = lane & 7;
                float yv = ws[i8] * ob[0];
                #pragma unroll
                for (int l = 1; l < OLEN; ++l) yv = fmaf(ws[l * ILEN + i8], ob[l], yv);
                if (lane < 8) ylds[lane] = yv * inv;
            }
            __syncthreads();
        } else {
            // final iteration: write out (wave 0) and probs (all threads)
            if (wid == 0) {
                float sv = (lane < 8) ? (red[0][lane] + red[1][lane]) : 0.0f;
                float sb[ILEN];
                #pragma unroll
                for (int i = 0; i < ILEN; ++i) sb[i] = __shfl(sv, i, 64);
                const int l16 = lane & 15;
                const float4 w0 = *(const float4*)&ws[l16 * ILEN];
                const float4 w1 = *(const float4*)&ws[l16 * ILEN + 4];
                float outl = w0.x * sb[0];
                outl = fmaf(w0.y, sb[1], outl);
                outl = fmaf(w0.z, sb[2], outl);
                outl = fmaf(w0.w, sb[3], outl);
                outl = fmaf(w1.x, sb[4], outl);
                outl = fmaf(w1.y, sb[5], outl);
                outl = fmaf(w1.z, sb[6], outl);
                outl = fmaf(w1.w, sb[7], outl);
                outl *= zinv;
                if (lane < OLEN) dout[(size_t)blockIdx.x * OLEN + lane] = outl;
            }
            float* probp = dout + (size_t)probs_base + (size_t)blockIdx.x * NCAPS;
            #pragma unroll
            for (int k = 0; k < RPT; ++k) probp[tid + k * T] = e[k] * zinv;
        }
    }
}

extern "C" void kernel_launch(void* const* d_in, const int* in_sizes, int n_in,
                              void* d_out, int out_size, void* d_ws, size_t ws_size,
                              hipStream_t stream) {
    const float* x = (const float*)d_in[0];
    const float* w = (const float*)d_in[1];
    float* out = (float*)d_out;
    const int Bv = in_sizes[0] / (NCAPS * ILEN);   // 64
    const int nblocks = Bv * OCAPS;                // 4096
    const int probs_base = nblocks * OLEN;         // 65536
    caps_kernel<<<dim3(nblocks), dim3(T), 0, stream>>>(x, w, out, probs_base);
}